// Round 5
// baseline (107.156 us; speedup 1.0000x reference)
//
#include <hip/hip_runtime.h>

#define Bn  4
#define TEn 512
#define TDn 256
#define HEn 128
#define HDn 256

__device__ __forceinline__ float tanh_fast(float x) {
    // tanh(x) = 1 - 2/(exp2(k*x)+1), k = 2*log2(e); exact at +/-inf
    float e = __builtin_amdgcn_exp2f(x * 2.8853900817779268f);
    return 1.0f - 2.0f * __builtin_amdgcn_rcpf(e + 1.0f);
}

// One launch, two jobs (independent, overlap on the grid):
//  blocks [0,256):   Ws[r,c] = sum_k enc[r,k]*W[k,c]   (8 rows/block)
//  blocks [256,512): Uh[r,f] = sum_k dec[r,k]*U[k,f]   (4 rows/block, 2 k-parts)
__global__ __launch_bounds__(512) void prep_kernel(
    const float* __restrict__ enc, const float* __restrict__ W,
    const float* __restrict__ dec, const float* __restrict__ U,
    float* __restrict__ Ws, float* __restrict__ Uh)
{
    __shared__ __align__(16) float lds[2048];   // 8 KB, shared by both jobs
    const int tid = threadIdx.x;
    if (blockIdx.x < 256) {
        // ---- Ws job: 8 enc rows staged in LDS, thread owns (row, 2 cols)
        const int r0 = blockIdx.x * 8;
        *(float2*)&lds[2 * tid] = *(const float2*)(enc + r0 * HEn + 2 * tid);
        __syncthreads();
        const int c2 = (tid & 63) * 2;
        const int rl = tid >> 6;                 // wave-uniform
        const float* er = lds + rl * HEn;
        float a0 = 0.f, a1 = 0.f;
        #pragma unroll 4
        for (int k = 0; k < HEn; k += 4) {
            const float4 e4 = *(const float4*)(er + k);
            const float2 w0 = *(const float2*)(W + (k + 0) * HEn + c2);
            const float2 w1 = *(const float2*)(W + (k + 1) * HEn + c2);
            const float2 w2 = *(const float2*)(W + (k + 2) * HEn + c2);
            const float2 w3 = *(const float2*)(W + (k + 3) * HEn + c2);
            a0 = fmaf(e4.x, w0.x, a0); a1 = fmaf(e4.x, w0.y, a1);
            a0 = fmaf(e4.y, w1.x, a0); a1 = fmaf(e4.y, w1.y, a1);
            a0 = fmaf(e4.z, w2.x, a0); a1 = fmaf(e4.z, w2.y, a1);
            a0 = fmaf(e4.w, w3.x, a0); a1 = fmaf(e4.w, w3.y, a1);
        }
        float2 o; o.x = a0; o.y = a1;
        *(float2*)(Ws + (r0 + rl) * HEn + c2) = o;
    } else {
        // ---- Uh job: 4 dec rows staged, thread owns (row, 2 f, k-half)
        const int r0 = (blockIdx.x - 256) * 4;
        *(float2*)&lds[2 * tid] = *(const float2*)(dec + r0 * HDn + 2 * tid);
        __syncthreads();
        const int f2 = (tid & 63) * 2;
        const int rl = (tid >> 6) & 3;           // wave-uniform
        const int kp = tid >> 8;                 // 0 or 1
        const float* d = lds + rl * HDn + kp * 128;
        float a0 = 0.f, a1 = 0.f;
        #pragma unroll 4
        for (int k = 0; k < 128; k += 4) {
            const float4 d4 = *(const float4*)(d + k);
            const float2 u0 = *(const float2*)(U + (kp * 128 + k + 0) * HEn + f2);
            const float2 u1 = *(const float2*)(U + (kp * 128 + k + 1) * HEn + f2);
            const float2 u2 = *(const float2*)(U + (kp * 128 + k + 2) * HEn + f2);
            const float2 u3 = *(const float2*)(U + (kp * 128 + k + 3) * HEn + f2);
            a0 = fmaf(d4.x, u0.x, a0); a1 = fmaf(d4.x, u0.y, a1);
            a0 = fmaf(d4.y, u1.x, a0); a1 = fmaf(d4.y, u1.y, a1);
            a0 = fmaf(d4.z, u2.x, a0); a1 = fmaf(d4.z, u2.y, a1);
            a0 = fmaf(d4.w, u3.x, a0); a1 = fmaf(d4.w, u3.y, a1);
        }
        __syncthreads();                         // lds reuse for reduction
        __shared__ float part[2][4][HEn];
        part[kp][rl][f2]     = a0;
        part[kp][rl][f2 + 1] = a1;
        __syncthreads();
        if (kp == 0) {
            float2 o;
            o.x = part[0][rl][f2]     + part[1][rl][f2];
            o.y = part[0][rl][f2 + 1] + part[1][rl][f2 + 1];
            *(float2*)(Uh + (r0 + rl) * HEn + f2) = o;
        }
    }
}

// Scores + softmax only: block per (b, t-pair), 512 thr, wave owns 64 s.
__global__ __launch_bounds__(512, 6) void score_kernel(
    const float* __restrict__ V, const float* __restrict__ Ws,
    const float* __restrict__ Uh, float* __restrict__ e_out)
{
    const int bp   = blockIdx.x;        // b*128 + tq
    const int b    = bp >> 7;
    const int bt0  = b * TDn + (bp & 127) * 2;
    const int tid  = threadIdx.x;
    const int lane = tid & 63;
    const int wave = tid >> 6;          // 0..7

    __shared__ __align__(16) float sc0[TEn];
    __shared__ __align__(16) float sc1[TEn];
    __shared__ float redm[2][8];
    __shared__ float reds[2][8];

    // ---- scores: lane = (s_sub = lane&7) x (f_grp = lane>>3, 16 f each)
    {
        const int s_sub = lane & 7;
        const int f0    = (lane >> 3) * 16;
        float4 vv[4], u0[4], u1[4];
        #pragma unroll
        for (int j = 0; j < 4; ++j) {
            vv[j] = *(const float4*)(V + f0 + 4 * j);
            u0[j] = *(const float4*)(Uh + bt0 * HEn + f0 + 4 * j);
            u1[j] = *(const float4*)(Uh + (bt0 + 1) * HEn + f0 + 4 * j);
        }
        const float* wsb = Ws + (b * TEn + wave * 64) * HEn;
        #pragma unroll 2
        for (int ci = 0; ci < 8; ++ci) {
            const float* wp = wsb + (ci * 8 + s_sub) * HEn + f0;
            float x0 = 0.f, x1 = 0.f;
            #pragma unroll
            for (int j = 0; j < 4; ++j) {
                float4 w = ((const float4*)wp)[j];     // one load, two chains
                x0 = fmaf(vv[j].x, tanh_fast(w.x + u0[j].x), x0);
                x1 = fmaf(vv[j].x, tanh_fast(w.x + u1[j].x), x1);
                x0 = fmaf(vv[j].y, tanh_fast(w.y + u0[j].y), x0);
                x1 = fmaf(vv[j].y, tanh_fast(w.y + u1[j].y), x1);
                x0 = fmaf(vv[j].z, tanh_fast(w.z + u0[j].z), x0);
                x1 = fmaf(vv[j].z, tanh_fast(w.z + u1[j].z), x1);
                x0 = fmaf(vv[j].w, tanh_fast(w.w + u0[j].w), x0);
                x1 = fmaf(vv[j].w, tanh_fast(w.w + u1[j].w), x1);
            }
            x0 += __shfl_xor(x0, 8, 64);
            x1 += __shfl_xor(x1, 8, 64);
            x0 += __shfl_xor(x0, 16, 64);
            x1 += __shfl_xor(x1, 16, 64);
            x0 += __shfl_xor(x0, 32, 64);
            x1 += __shfl_xor(x1, 32, 64);
            if (lane < 8) {
                sc0[wave * 64 + ci * 8 + lane] = x0;
                sc1[wave * 64 + ci * 8 + lane] = x1;
            }
        }
    }
    __syncthreads();

    // ---- softmax over both rows; thread tid owns s = tid
    const float v0 = sc0[tid];
    const float v1 = sc1[tid];
    float m0 = v0, m1 = v1;
    #pragma unroll
    for (int off = 32; off; off >>= 1) {
        m0 = fmaxf(m0, __shfl_xor(m0, off, 64));
        m1 = fmaxf(m1, __shfl_xor(m1, off, 64));
    }
    if (lane == 0) { redm[0][wave] = m0; redm[1][wave] = m1; }
    __syncthreads();
    float bm0 = redm[0][0], bm1 = redm[1][0];
    #pragma unroll
    for (int w = 1; w < 8; ++w) {
        bm0 = fmaxf(bm0, redm[0][w]);
        bm1 = fmaxf(bm1, redm[1][w]);
    }
    const float ex0 = __expf(v0 - bm0);
    const float ex1 = __expf(v1 - bm1);
    float s0 = ex0, s1 = ex1;
    #pragma unroll
    for (int off = 32; off; off >>= 1) {
        s0 += __shfl_xor(s0, off, 64);
        s1 += __shfl_xor(s1, off, 64);
    }
    if (lane == 0) { reds[0][wave] = s0; reds[1][wave] = s1; }
    __syncthreads();
    float bs0 = reds[0][0], bs1 = reds[1][0];
    #pragma unroll
    for (int w = 1; w < 8; ++w) { bs0 += reds[0][w]; bs1 += reds[1][w]; }
    e_out[bt0 * TEn + tid]       = ex0 * __builtin_amdgcn_rcpf(bs0);
    e_out[(bt0 + 1) * TEn + tid] = ex1 * __builtin_amdgcn_rcpf(bs1);
}

// Context GEMM: c[bt, h] = sum_s e[bt, s] * enc[b, s, h]; block per t-pair.
__global__ __launch_bounds__(512, 4) void ctx_kernel(
    const float* __restrict__ enc, const float* __restrict__ e_out,
    float* __restrict__ c_out)
{
    const int bp  = blockIdx.x;
    const int b   = bp >> 7;
    const int bt0 = b * TDn + (bp & 127) * 2;
    const int tid = threadIdx.x;

    __shared__ __align__(16) float e_lds[2][TEn];     // 4 KB
    __shared__ __align__(16) float part[16][2 * HEn]; // 16 KB

    e_lds[0][tid] = e_out[bt0 * TEn + tid];
    e_lds[1][tid] = e_out[(bt0 + 1) * TEn + tid];
    __syncthreads();

    // thread = (hl = tid&31 -> h = 4*hl..) x (sp = tid>>5, 32 s each)
    const int hl = tid & 31;
    const int sp = tid >> 5;                          // 0..15
    const float* eb = enc + (b * TEn + sp * 32) * HEn + hl * 4;
    float4 a0 = {0,0,0,0}, a1 = {0,0,0,0};
    #pragma unroll 4
    for (int i = 0; i < 32; ++i) {
        const int s = sp * 32 + i;
        const float4 ev = *(const float4*)(eb + i * HEn);  // one load, 2 accs
        const float w0 = e_lds[0][s], w1 = e_lds[1][s];
        a0.x = fmaf(w0, ev.x, a0.x); a1.x = fmaf(w1, ev.x, a1.x);
        a0.y = fmaf(w0, ev.y, a0.y); a1.y = fmaf(w1, ev.y, a1.y);
        a0.z = fmaf(w0, ev.z, a0.z); a1.z = fmaf(w1, ev.z, a1.z);
        a0.w = fmaf(w0, ev.w, a0.w); a1.w = fmaf(w1, ev.w, a1.w);
    }
    *(float4*)&part[sp][hl * 4]       = a0;
    *(float4*)&part[sp][HEn + hl * 4] = a1;
    __syncthreads();
    if (tid < 2 * HEn) {
        const int r = tid >> 7, h = tid & 127;
        float s = 0.f;
        #pragma unroll
        for (int p = 0; p < 16; ++p) s += part[p][r * HEn + h];
        c_out[(bt0 + r) * HEn + h] = s;
    }
}

extern "C" void kernel_launch(void* const* d_in, const int* in_sizes, int n_in,
                              void* d_out, int out_size, void* d_ws, size_t ws_size,
                              hipStream_t stream) {
    const float* enc = (const float*)d_in[0];   // [B,TE,HE]
    const float* dec = (const float*)d_in[1];   // [B,TD,HD]
    const float* W   = (const float*)d_in[2];   // [HE,HE]
    const float* U   = (const float*)d_in[3];   // [HD,HE]
    const float* V   = (const float*)d_in[4];   // [HE,1]
    float* out   = (float*)d_out;
    float* c_out = out;                         // [B,TD,HE]
    float* e_out = out + Bn * TDn * HEn;        // [B,TD,TE]
    float* Ws    = (float*)d_ws;                          // 1 MB
    float* Uh    = (float*)d_ws + Bn * TEn * HEn;         // 512 KB

    prep_kernel<<<512, 512, 0, stream>>>(enc, W, dec, U, Ws, Uh);
    score_kernel<<<Bn * TDn / 2, 512, 0, stream>>>(V, Ws, Uh, e_out);
    ctx_kernel<<<Bn * TDn / 2, 512, 0, stream>>>(enc, e_out, c_out);
}

// Round 6
// 103.237 us; speedup vs baseline: 1.0380x; 1.0380x over previous
//
#include <hip/hip_runtime.h>

#define Bn  4
#define TEn 512
#define TDn 256
#define HEn 128
#define HDn 256

#define LOG2E 1.4426950408889634f

__device__ __forceinline__ float tanh_fast(float x) {
    // tanh(x) = 1 - 2/(exp2(k*x)+1), k = 2*log2(e); exact at +/-inf
    float e = __builtin_amdgcn_exp2f(x * (2.0f * LOG2E));
    return 1.0f - 2.0f * __builtin_amdgcn_rcpf(e + 1.0f);
}

// One launch, two jobs (independent, overlap on the grid):
//  blocks [0,256):   Ws[r,c] = sum_k enc[r,k]*W[k,c]   (8 rows/block)
//  blocks [256,512): Uh[r,f] = sum_k dec[r,k]*U[k,f]   (4 rows/block, 2 k-parts)
__global__ __launch_bounds__(512) void prep_kernel(
    const float* __restrict__ enc, const float* __restrict__ W,
    const float* __restrict__ dec, const float* __restrict__ U,
    float* __restrict__ Ws, float* __restrict__ Uh)
{
    __shared__ __align__(16) float lds[2048];   // 8 KB, shared by both jobs
    const int tid = threadIdx.x;
    if (blockIdx.x < 256) {
        // ---- Ws job: 8 enc rows staged in LDS, thread owns (row, 2 cols)
        const int r0 = blockIdx.x * 8;
        *(float2*)&lds[2 * tid] = *(const float2*)(enc + r0 * HEn + 2 * tid);
        __syncthreads();
        const int c2 = (tid & 63) * 2;
        const int rl = tid >> 6;                 // wave-uniform
        const float* er = lds + rl * HEn;
        float a0 = 0.f, a1 = 0.f;
        #pragma unroll 4
        for (int k = 0; k < HEn; k += 4) {
            const float4 e4 = *(const float4*)(er + k);
            const float2 w0 = *(const float2*)(W + (k + 0) * HEn + c2);
            const float2 w1 = *(const float2*)(W + (k + 1) * HEn + c2);
            const float2 w2 = *(const float2*)(W + (k + 2) * HEn + c2);
            const float2 w3 = *(const float2*)(W + (k + 3) * HEn + c2);
            a0 = fmaf(e4.x, w0.x, a0); a1 = fmaf(e4.x, w0.y, a1);
            a0 = fmaf(e4.y, w1.x, a0); a1 = fmaf(e4.y, w1.y, a1);
            a0 = fmaf(e4.z, w2.x, a0); a1 = fmaf(e4.z, w2.y, a1);
            a0 = fmaf(e4.w, w3.x, a0); a1 = fmaf(e4.w, w3.y, a1);
        }
        float2 o; o.x = a0; o.y = a1;
        *(float2*)(Ws + (r0 + rl) * HEn + c2) = o;
    } else {
        // ---- Uh job: 4 dec rows staged, thread owns (row, 2 f, k-half)
        const int r0 = (blockIdx.x - 256) * 4;
        *(float2*)&lds[2 * tid] = *(const float2*)(dec + r0 * HDn + 2 * tid);
        __syncthreads();
        const int f2 = (tid & 63) * 2;
        const int rl = (tid >> 6) & 3;           // wave-uniform
        const int kp = tid >> 8;                 // 0 or 1
        const float* d = lds + rl * HDn + kp * 128;
        float a0 = 0.f, a1 = 0.f;
        #pragma unroll 4
        for (int k = 0; k < 128; k += 4) {
            const float4 d4 = *(const float4*)(d + k);
            const float2 u0 = *(const float2*)(U + (kp * 128 + k + 0) * HEn + f2);
            const float2 u1 = *(const float2*)(U + (kp * 128 + k + 1) * HEn + f2);
            const float2 u2 = *(const float2*)(U + (kp * 128 + k + 2) * HEn + f2);
            const float2 u3 = *(const float2*)(U + (kp * 128 + k + 3) * HEn + f2);
            a0 = fmaf(d4.x, u0.x, a0); a1 = fmaf(d4.x, u0.y, a1);
            a0 = fmaf(d4.y, u1.x, a0); a1 = fmaf(d4.y, u1.y, a1);
            a0 = fmaf(d4.z, u2.x, a0); a1 = fmaf(d4.z, u2.y, a1);
            a0 = fmaf(d4.w, u3.x, a0); a1 = fmaf(d4.w, u3.y, a1);
        }
        __syncthreads();                         // lds reuse for reduction
        __shared__ float part[2][4][HEn];
        part[kp][rl][f2]     = a0;
        part[kp][rl][f2 + 1] = a1;
        __syncthreads();
        if (kp == 0) {
            float2 o;
            o.x = part[0][rl][f2]     + part[1][rl][f2];
            o.y = part[0][rl][f2 + 1] + part[1][rl][f2 + 1];
            *(float2*)(Uh + (r0 + rl) * HEn + f2) = o;
        }
    }
}

// Fused scores + softmax + context: block per (b, t-pair), 512 thr.
// e kept in LDS between softmax and context (no global round-trip).
__global__ __launch_bounds__(512, 6) void attn_fused_kernel(
    const float* __restrict__ enc, const float* __restrict__ V,
    const float* __restrict__ Ws, const float* __restrict__ Uh,
    float* __restrict__ c_out, float* __restrict__ e_out)
{
    const int bp   = blockIdx.x;        // b*128 + tq
    const int b    = bp >> 7;
    const int bt0  = b * TDn + (bp & 127) * 2;
    const int tid  = threadIdx.x;
    const int lane = tid & 63;
    const int wave = tid >> 6;          // 0..7

    __shared__ __align__(16) float sc0[TEn];          // 2 KB
    __shared__ __align__(16) float sc1[TEn];          // 2 KB
    __shared__ __align__(16) float part[16][2 * HEn]; // 16 KB
    __shared__ float redm[2][8];
    __shared__ float reds[2][8];

    // ---- scores: lane = (s_sub = lane&7) x (f_grp = lane>>3, 16 f each)
    {
        const int s_sub = lane & 7;
        const int f0    = (lane >> 3) * 16;
        float4 vv[4], u0[4], u1[4];
        #pragma unroll
        for (int j = 0; j < 4; ++j) {
            vv[j] = *(const float4*)(V + f0 + 4 * j);
            u0[j] = *(const float4*)(Uh + bt0 * HEn + f0 + 4 * j);
            u1[j] = *(const float4*)(Uh + (bt0 + 1) * HEn + f0 + 4 * j);
        }
        const float* wsb = Ws + (b * TEn + wave * 64) * HEn;
        #pragma unroll 2
        for (int ci = 0; ci < 8; ++ci) {
            const float* wp = wsb + (ci * 8 + s_sub) * HEn + f0;
            float x0 = 0.f, x1 = 0.f;
            #pragma unroll
            for (int j = 0; j < 4; ++j) {
                float4 w = ((const float4*)wp)[j];     // one load, two chains
                x0 = fmaf(vv[j].x, tanh_fast(w.x + u0[j].x), x0);
                x1 = fmaf(vv[j].x, tanh_fast(w.x + u1[j].x), x1);
                x0 = fmaf(vv[j].y, tanh_fast(w.y + u0[j].y), x0);
                x1 = fmaf(vv[j].y, tanh_fast(w.y + u1[j].y), x1);
                x0 = fmaf(vv[j].z, tanh_fast(w.z + u0[j].z), x0);
                x1 = fmaf(vv[j].z, tanh_fast(w.z + u1[j].z), x1);
                x0 = fmaf(vv[j].w, tanh_fast(w.w + u0[j].w), x0);
                x1 = fmaf(vv[j].w, tanh_fast(w.w + u1[j].w), x1);
            }
            x0 += __shfl_xor(x0, 8, 64);
            x1 += __shfl_xor(x1, 8, 64);
            x0 += __shfl_xor(x0, 16, 64);
            x1 += __shfl_xor(x1, 16, 64);
            x0 += __shfl_xor(x0, 32, 64);
            x1 += __shfl_xor(x1, 32, 64);
            if (lane < 8) {
                sc0[wave * 64 + ci * 8 + lane] = x0;
                sc1[wave * 64 + ci * 8 + lane] = x1;
            }
        }
    }
    __syncthreads();

    // ---- softmax over both rows; thread tid owns s = tid
    {
        const float v0 = sc0[tid];
        const float v1 = sc1[tid];
        float m0 = v0, m1 = v1;
        #pragma unroll
        for (int off = 32; off; off >>= 1) {
            m0 = fmaxf(m0, __shfl_xor(m0, off, 64));
            m1 = fmaxf(m1, __shfl_xor(m1, off, 64));
        }
        if (lane == 0) { redm[0][wave] = m0; redm[1][wave] = m1; }
        __syncthreads();
        float bm0 = redm[0][0], bm1 = redm[1][0];
        #pragma unroll
        for (int w = 1; w < 8; ++w) {
            bm0 = fmaxf(bm0, redm[0][w]);
            bm1 = fmaxf(bm1, redm[1][w]);
        }
        const float ex0 = __builtin_amdgcn_exp2f((v0 - bm0) * LOG2E);
        const float ex1 = __builtin_amdgcn_exp2f((v1 - bm1) * LOG2E);
        float s0 = ex0, s1 = ex1;
        #pragma unroll
        for (int off = 32; off; off >>= 1) {
            s0 += __shfl_xor(s0, off, 64);
            s1 += __shfl_xor(s1, off, 64);
        }
        if (lane == 0) { reds[0][wave] = s0; reds[1][wave] = s1; }
        __syncthreads();
        float bs0 = reds[0][0], bs1 = reds[1][0];
        #pragma unroll
        for (int w = 1; w < 8; ++w) { bs0 += reds[0][w]; bs1 += reds[1][w]; }
        const float e0 = ex0 * __builtin_amdgcn_rcpf(bs0);
        const float e1 = ex1 * __builtin_amdgcn_rcpf(bs1);
        e_out[bt0 * TEn + tid]       = e0;
        e_out[(bt0 + 1) * TEn + tid] = e1;
        sc0[tid] = e0;               // same thread read this slot; no race
        sc1[tid] = e1;
    }
    __syncthreads();

    // ---- context: c[bt0+r, h] = sum_s e_r[s] * enc[b, s, h]
    // thread = (hl = tid&31 -> h = 4*hl..) x (sp = tid>>5, 32 s each)
    {
        const int hl = tid & 31;
        const int sp = tid >> 5;                      // 0..15
        const float* eb = enc + (b * TEn + sp * 32) * HEn + hl * 4;
        float4 a0 = {0,0,0,0}, a1 = {0,0,0,0};
        #pragma unroll 4
        for (int i = 0; i < 32; ++i) {
            const int s = sp * 32 + i;
            const float4 ev = *(const float4*)(eb + i * HEn);  // one load, 2 accs
            const float w0 = sc0[s], w1 = sc1[s];
            a0.x = fmaf(w0, ev.x, a0.x); a1.x = fmaf(w1, ev.x, a1.x);
            a0.y = fmaf(w0, ev.y, a0.y); a1.y = fmaf(w1, ev.y, a1.y);
            a0.z = fmaf(w0, ev.z, a0.z); a1.z = fmaf(w1, ev.z, a1.z);
            a0.w = fmaf(w0, ev.w, a0.w); a1.w = fmaf(w1, ev.w, a1.w);
        }
        *(float4*)&part[sp][hl * 4]       = a0;
        *(float4*)&part[sp][HEn + hl * 4] = a1;
    }
    __syncthreads();
    if (tid < 2 * HEn) {
        const int r = tid >> 7, h = tid & 127;
        float s = 0.f;
        #pragma unroll
        for (int p = 0; p < 16; ++p) s += part[p][r * HEn + h];
        c_out[(bt0 + r) * HEn + h] = s;
    }
}

extern "C" void kernel_launch(void* const* d_in, const int* in_sizes, int n_in,
                              void* d_out, int out_size, void* d_ws, size_t ws_size,
                              hipStream_t stream) {
    const float* enc = (const float*)d_in[0];   // [B,TE,HE]
    const float* dec = (const float*)d_in[1];   // [B,TD,HD]
    const float* W   = (const float*)d_in[2];   // [HE,HE]
    const float* U   = (const float*)d_in[3];   // [HD,HE]
    const float* V   = (const float*)d_in[4];   // [HE,1]
    float* out   = (float*)d_out;
    float* c_out = out;                         // [B,TD,HE]
    float* e_out = out + Bn * TDn * HEn;        // [B,TD,TE]
    float* Ws    = (float*)d_ws;                          // 1 MB
    float* Uh    = (float*)d_ws + Bn * TEn * HEn;         // 512 KB

    prep_kernel<<<512, 512, 0, stream>>>(enc, W, dec, U, Ws, Uh);
    attn_fused_kernel<<<Bn * TDn / 2, 512, 0, stream>>>(enc, V, Ws, Uh, c_out, e_out);
}

// Round 7
// 101.392 us; speedup vs baseline: 1.0569x; 1.0182x over previous
//
#include <hip/hip_runtime.h>

#define Bn  4
#define TEn 512
#define TDn 256
#define HEn 128
#define HDn 256

#define LOG2E 1.4426950408889634f
#define K2    2.8853900817779268f   // 2*log2(e), folded into Ws/Uh at prep time

// One launch, two jobs (independent, overlap on the grid):
//  blocks [0,256):   Ws[r,c] = K2 * sum_k enc[r,k]*W[k,c]   (8 rows/block)
//  blocks [256,512): Uh[r,f] = K2 * sum_k dec[r,k]*U[k,f]   (4 rows/block, 2 k-parts)
__global__ __launch_bounds__(512) void prep_kernel(
    const float* __restrict__ enc, const float* __restrict__ W,
    const float* __restrict__ dec, const float* __restrict__ U,
    float* __restrict__ Ws, float* __restrict__ Uh)
{
    __shared__ __align__(16) float lds[2048];   // 8 KB, shared by both jobs
    const int tid = threadIdx.x;
    if (blockIdx.x < 256) {
        // ---- Ws job: 8 enc rows staged in LDS, thread owns (row, 2 cols)
        const int r0 = blockIdx.x * 8;
        *(float2*)&lds[2 * tid] = *(const float2*)(enc + r0 * HEn + 2 * tid);
        __syncthreads();
        const int c2 = (tid & 63) * 2;
        const int rl = tid >> 6;                 // wave-uniform
        const float* er = lds + rl * HEn;
        float a0 = 0.f, a1 = 0.f;
        #pragma unroll 4
        for (int k = 0; k < HEn; k += 4) {
            const float4 e4 = *(const float4*)(er + k);
            const float2 w0 = *(const float2*)(W + (k + 0) * HEn + c2);
            const float2 w1 = *(const float2*)(W + (k + 1) * HEn + c2);
            const float2 w2 = *(const float2*)(W + (k + 2) * HEn + c2);
            const float2 w3 = *(const float2*)(W + (k + 3) * HEn + c2);
            a0 = fmaf(e4.x, w0.x, a0); a1 = fmaf(e4.x, w0.y, a1);
            a0 = fmaf(e4.y, w1.x, a0); a1 = fmaf(e4.y, w1.y, a1);
            a0 = fmaf(e4.z, w2.x, a0); a1 = fmaf(e4.z, w2.y, a1);
            a0 = fmaf(e4.w, w3.x, a0); a1 = fmaf(e4.w, w3.y, a1);
        }
        float2 o; o.x = a0 * K2; o.y = a1 * K2;
        *(float2*)(Ws + (r0 + rl) * HEn + c2) = o;
    } else {
        // ---- Uh job: 4 dec rows staged, thread owns (row, 2 f, k-half)
        const int r0 = (blockIdx.x - 256) * 4;
        *(float2*)&lds[2 * tid] = *(const float2*)(dec + r0 * HDn + 2 * tid);
        __syncthreads();
        const int f2 = (tid & 63) * 2;
        const int rl = (tid >> 6) & 3;           // wave-uniform
        const int kp = tid >> 8;                 // 0 or 1
        const float* d = lds + rl * HDn + kp * 128;
        float a0 = 0.f, a1 = 0.f;
        #pragma unroll 4
        for (int k = 0; k < 128; k += 4) {
            const float4 d4 = *(const float4*)(d + k);
            const float2 u0 = *(const float2*)(U + (kp * 128 + k + 0) * HEn + f2);
            const float2 u1 = *(const float2*)(U + (kp * 128 + k + 1) * HEn + f2);
            const float2 u2 = *(const float2*)(U + (kp * 128 + k + 2) * HEn + f2);
            const float2 u3 = *(const float2*)(U + (kp * 128 + k + 3) * HEn + f2);
            a0 = fmaf(d4.x, u0.x, a0); a1 = fmaf(d4.x, u0.y, a1);
            a0 = fmaf(d4.y, u1.x, a0); a1 = fmaf(d4.y, u1.y, a1);
            a0 = fmaf(d4.z, u2.x, a0); a1 = fmaf(d4.z, u2.y, a1);
            a0 = fmaf(d4.w, u3.x, a0); a1 = fmaf(d4.w, u3.y, a1);
        }
        __syncthreads();                         // lds reuse for reduction
        __shared__ float part[2][4][HEn];
        part[kp][rl][f2]     = a0;
        part[kp][rl][f2 + 1] = a1;
        __syncthreads();
        if (kp == 0) {
            float2 o;
            o.x = (part[0][rl][f2]     + part[1][rl][f2])     * K2;
            o.y = (part[0][rl][f2 + 1] + part[1][rl][f2 + 1]) * K2;
            *(float2*)(Uh + (r0 + rl) * HEn + f2) = o;
        }
    }
}

// Fused scores + softmax + context: block per (b, t-pair), 512 thr.
// Score math (Ws,Uh pre-scaled by K2): sum_f V*tanh = sum(V) - sum 2V*rcp(exp2(kx)+1)
// -> per element exactly: v_add, v_exp, v_add, v_rcp, v_fma.
__global__ __launch_bounds__(512, 4) void attn_fused_kernel(
    const float* __restrict__ enc, const float* __restrict__ V,
    const float* __restrict__ Ws, const float* __restrict__ Uh,
    float* __restrict__ c_out, float* __restrict__ e_out)
{
    const int bp   = blockIdx.x;        // b*128 + tq
    const int b    = bp >> 7;
    const int bt0  = b * TDn + (bp & 127) * 2;
    const int tid  = threadIdx.x;
    const int lane = tid & 63;
    const int wave = tid >> 6;          // 0..7

    __shared__ __align__(16) float sc0[TEn];          // 2 KB
    __shared__ __align__(16) float sc1[TEn];          // 2 KB
    __shared__ __align__(16) float part[16][2 * HEn]; // 16 KB
    __shared__ float redm[2][8];
    __shared__ float reds[2][8];

    // ---- scores: lane = (s_sub = lane&7) x (f_grp = lane>>3, 16 f each)
    {
        const int s_sub = lane & 7;
        const int f0    = (lane >> 3) * 16;
        float4 mv[4], u0[4], u1[4];
        float sv = 0.f;
        #pragma unroll
        for (int j = 0; j < 4; ++j) {
            const float4 v = *(const float4*)(V + f0 + 4 * j);
            sv += v.x + v.y + v.z + v.w;
            mv[j].x = -2.f * v.x; mv[j].y = -2.f * v.y;
            mv[j].z = -2.f * v.z; mv[j].w = -2.f * v.w;
            u0[j] = *(const float4*)(Uh + bt0 * HEn + f0 + 4 * j);
            u1[j] = *(const float4*)(Uh + (bt0 + 1) * HEn + f0 + 4 * j);
        }
        const float* wsb = Ws + (b * TEn + wave * 64) * HEn;
        #pragma unroll 2
        for (int ci = 0; ci < 8; ++ci) {
            const float* wp = wsb + (ci * 8 + s_sub) * HEn + f0;
            float x0 = sv, x1 = sv;
            #pragma unroll
            for (int j = 0; j < 4; ++j) {
                const float4 w = ((const float4*)wp)[j];   // one load, two chains
                float r;
                r = __builtin_amdgcn_rcpf(__builtin_amdgcn_exp2f(w.x + u0[j].x) + 1.f);
                x0 = fmaf(mv[j].x, r, x0);
                r = __builtin_amdgcn_rcpf(__builtin_amdgcn_exp2f(w.x + u1[j].x) + 1.f);
                x1 = fmaf(mv[j].x, r, x1);
                r = __builtin_amdgcn_rcpf(__builtin_amdgcn_exp2f(w.y + u0[j].y) + 1.f);
                x0 = fmaf(mv[j].y, r, x0);
                r = __builtin_amdgcn_rcpf(__builtin_amdgcn_exp2f(w.y + u1[j].y) + 1.f);
                x1 = fmaf(mv[j].y, r, x1);
                r = __builtin_amdgcn_rcpf(__builtin_amdgcn_exp2f(w.z + u0[j].z) + 1.f);
                x0 = fmaf(mv[j].z, r, x0);
                r = __builtin_amdgcn_rcpf(__builtin_amdgcn_exp2f(w.z + u1[j].z) + 1.f);
                x1 = fmaf(mv[j].z, r, x1);
                r = __builtin_amdgcn_rcpf(__builtin_amdgcn_exp2f(w.w + u0[j].w) + 1.f);
                x0 = fmaf(mv[j].w, r, x0);
                r = __builtin_amdgcn_rcpf(__builtin_amdgcn_exp2f(w.w + u1[j].w) + 1.f);
                x1 = fmaf(mv[j].w, r, x1);
            }
            x0 += __shfl_xor(x0, 8, 64);
            x1 += __shfl_xor(x1, 8, 64);
            x0 += __shfl_xor(x0, 16, 64);
            x1 += __shfl_xor(x1, 16, 64);
            x0 += __shfl_xor(x0, 32, 64);
            x1 += __shfl_xor(x1, 32, 64);
            if (lane < 8) {
                sc0[wave * 64 + ci * 8 + lane] = x0;
                sc1[wave * 64 + ci * 8 + lane] = x1;
            }
        }
    }
    __syncthreads();

    // ---- softmax over both rows; thread tid owns s = tid
    {
        const float v0 = sc0[tid];
        const float v1 = sc1[tid];
        float m0 = v0, m1 = v1;
        #pragma unroll
        for (int off = 32; off; off >>= 1) {
            m0 = fmaxf(m0, __shfl_xor(m0, off, 64));
            m1 = fmaxf(m1, __shfl_xor(m1, off, 64));
        }
        if (lane == 0) { redm[0][wave] = m0; redm[1][wave] = m1; }
        __syncthreads();
        float bm0 = redm[0][0], bm1 = redm[1][0];
        #pragma unroll
        for (int w = 1; w < 8; ++w) {
            bm0 = fmaxf(bm0, redm[0][w]);
            bm1 = fmaxf(bm1, redm[1][w]);
        }
        const float ex0 = __builtin_amdgcn_exp2f((v0 - bm0) * LOG2E);
        const float ex1 = __builtin_amdgcn_exp2f((v1 - bm1) * LOG2E);
        float s0 = ex0, s1 = ex1;
        #pragma unroll
        for (int off = 32; off; off >>= 1) {
            s0 += __shfl_xor(s0, off, 64);
            s1 += __shfl_xor(s1, off, 64);
        }
        if (lane == 0) { reds[0][wave] = s0; reds[1][wave] = s1; }
        __syncthreads();
        float bs0 = reds[0][0], bs1 = reds[1][0];
        #pragma unroll
        for (int w = 1; w < 8; ++w) { bs0 += reds[0][w]; bs1 += reds[1][w]; }
        const float e0 = ex0 * __builtin_amdgcn_rcpf(bs0);
        const float e1 = ex1 * __builtin_amdgcn_rcpf(bs1);
        e_out[bt0 * TEn + tid]       = e0;
        e_out[(bt0 + 1) * TEn + tid] = e1;
        sc0[tid] = e0;               // same thread read this slot; no race
        sc1[tid] = e1;
    }
    __syncthreads();

    // ---- context: c[bt0+r, h] = sum_s e_r[s] * enc[b, s, h]
    // thread = (hl = tid&31 -> h = 4*hl..) x (sp = tid>>5, 32 s each)
    {
        const int hl = tid & 31;
        const int sp = tid >> 5;                      // 0..15
        const float* eb = enc + (b * TEn + sp * 32) * HEn + hl * 4;
        float4 a0 = {0,0,0,0}, a1 = {0,0,0,0};
        #pragma unroll 4
        for (int i = 0; i < 32; ++i) {
            const int s = sp * 32 + i;
            const float4 ev = *(const float4*)(eb + i * HEn);  // one load, 2 accs
            const float w0 = sc0[s], w1 = sc1[s];
            a0.x = fmaf(w0, ev.x, a0.x); a1.x = fmaf(w1, ev.x, a1.x);
            a0.y = fmaf(w0, ev.y, a0.y); a1.y = fmaf(w1, ev.y, a1.y);
            a0.z = fmaf(w0, ev.z, a0.z); a1.z = fmaf(w1, ev.z, a1.z);
            a0.w = fmaf(w0, ev.w, a0.w); a1.w = fmaf(w1, ev.w, a1.w);
        }
        *(float4*)&part[sp][hl * 4]       = a0;
        *(float4*)&part[sp][HEn + hl * 4] = a1;
    }
    __syncthreads();
    if (tid < 2 * HEn) {
        const int r = tid >> 7, h = tid & 127;
        float s = 0.f;
        #pragma unroll
        for (int p = 0; p < 16; ++p) s += part[p][r * HEn + h];
        c_out[(bt0 + r) * HEn + h] = s;
    }
}

extern "C" void kernel_launch(void* const* d_in, const int* in_sizes, int n_in,
                              void* d_out, int out_size, void* d_ws, size_t ws_size,
                              hipStream_t stream) {
    const float* enc = (const float*)d_in[0];   // [B,TE,HE]
    const float* dec = (const float*)d_in[1];   // [B,TD,HD]
    const float* W   = (const float*)d_in[2];   // [HE,HE]
    const float* U   = (const float*)d_in[3];   // [HD,HE]
    const float* V   = (const float*)d_in[4];   // [HE,1]
    float* out   = (float*)d_out;
    float* c_out = out;                         // [B,TD,HE]
    float* e_out = out + Bn * TDn * HEn;        // [B,TD,TE]
    float* Ws    = (float*)d_ws;                          // 1 MB (K2-scaled)
    float* Uh    = (float*)d_ws + Bn * TEn * HEn;         // 512 KB (K2-scaled)

    prep_kernel<<<512, 512, 0, stream>>>(enc, W, dec, U, Ws, Uh);
    attn_fused_kernel<<<Bn * TDn / 2, 512, 0, stream>>>(enc, V, Ws, Uh, c_out, e_out);
}

// Round 8
// 96.109 us; speedup vs baseline: 1.1149x; 1.0550x over previous
//
#include <hip/hip_runtime.h>

#define Bn  4
#define TEn 512
#define TDn 256
#define HEn 128
#define HDn 256

#define LOG2E 1.4426950408889634f
#define K2    2.8853900817779268f   // 2*log2(e), folded into Ws (prep) and Uh (inline)

// Ws[r,c] = K2 * sum_k enc[r,k]*W[k,c]; 8 rows/block staged in LDS.
__global__ __launch_bounds__(512) void ws_gemm_kernel(
    const float* __restrict__ enc, const float* __restrict__ W,
    float* __restrict__ Ws)
{
    __shared__ __align__(16) float lds[8 * HEn];   // 4 KB
    const int tid = threadIdx.x;
    const int r0  = blockIdx.x * 8;
    *(float2*)&lds[2 * tid] = *(const float2*)(enc + r0 * HEn + 2 * tid);
    __syncthreads();
    const int c2 = (tid & 63) * 2;
    const int rl = tid >> 6;                 // wave-uniform
    const float* er = lds + rl * HEn;
    float a0 = 0.f, a1 = 0.f;
    #pragma unroll 4
    for (int k = 0; k < HEn; k += 4) {
        const float4 e4 = *(const float4*)(er + k);
        const float2 w0 = *(const float2*)(W + (k + 0) * HEn + c2);
        const float2 w1 = *(const float2*)(W + (k + 1) * HEn + c2);
        const float2 w2 = *(const float2*)(W + (k + 2) * HEn + c2);
        const float2 w3 = *(const float2*)(W + (k + 3) * HEn + c2);
        a0 = fmaf(e4.x, w0.x, a0); a1 = fmaf(e4.x, w0.y, a1);
        a0 = fmaf(e4.y, w1.x, a0); a1 = fmaf(e4.y, w1.y, a1);
        a0 = fmaf(e4.z, w2.x, a0); a1 = fmaf(e4.z, w2.y, a1);
        a0 = fmaf(e4.w, w3.x, a0); a1 = fmaf(e4.w, w3.y, a1);
    }
    float2 o; o.x = a0 * K2; o.y = a1 * K2;
    *(float2*)(Ws + (r0 + rl) * HEn + c2) = o;
}

// Monolith: inline Uh + scores + softmax + context. Block per (b, t-pair).
// Score math (Ws,Uh pre-scaled by K2): sum_f V*tanh = sum(V) - sum 2V*rcp(exp2(kx)+1)
// -> per element exactly: v_add, v_exp, v_add, v_rcp, v_fma.
__global__ __launch_bounds__(512, 4) void attn_kernel(
    const float* __restrict__ enc, const float* __restrict__ dec,
    const float* __restrict__ U, const float* __restrict__ V,
    const float* __restrict__ Ws, float* __restrict__ c_out,
    float* __restrict__ e_out)
{
    const int bp   = blockIdx.x;        // b*128 + tq
    const int b    = bp >> 7;
    const int bt0  = b * TDn + (bp & 127) * 2;
    const int tid  = threadIdx.x;
    const int lane = tid & 63;
    const int wave = tid >> 6;          // 0..7

    __shared__ __align__(16) float dec_lds[2 * HDn];   // 2 KB
    __shared__ __align__(16) float uh0[HEn];           // 0.5 KB
    __shared__ __align__(16) float uh1[HEn];           // 0.5 KB
    __shared__ __align__(16) float sc0[TEn];           // 2 KB
    __shared__ __align__(16) float sc1[TEn];           // 2 KB
    __shared__ __align__(16) float part[16][2 * HEn];  // 16 KB
    __shared__ float redm[2][8];
    __shared__ float reds[2][8];

    // ---- stage both decoder rows (contiguous, coalesced 2 KB)
    dec_lds[tid] = dec[bt0 * HDn + tid];
    __syncthreads();

    // ---- Uh[t][f] = K2 * sum_k dec[bt0+t, k] * U[k, f]  (4 k-parts x 128 f)
    {
        const int f = tid & 127;
        const int p = tid >> 7;                        // wave-uniform
        const float* d0 = dec_lds + p * 64;            // LDS broadcast
        const float* d1 = dec_lds + HDn + p * 64;
        const float* u  = U + (p * 64) * HEn + f;      // coalesced
        float a0 = 0.f, a1 = 0.f;
        #pragma unroll 8
        for (int k = 0; k < 64; ++k) {
            const float uk = u[k * HEn];               // loaded once, used twice
            a0 = fmaf(d0[k], uk, a0);
            a1 = fmaf(d1[k], uk, a1);
        }
        part[p][f]       = a0;
        part[p][HEn + f] = a1;
    }
    __syncthreads();
    if (tid < 2 * HEn) {
        const int r = tid >> 7, f = tid & 127;
        const float s = part[0][r * HEn + f] + part[1][r * HEn + f]
                      + part[2][r * HEn + f] + part[3][r * HEn + f];
        (r ? uh1 : uh0)[f] = s * K2;
    }
    __syncthreads();

    // ---- scores: lane = (s_sub = lane&7) x (f_grp = lane>>3, 16 f each)
    {
        const int s_sub = lane & 7;
        const int f0    = (lane >> 3) * 16;
        float4 mv[4], u0[4], u1[4];
        float sv = 0.f;
        #pragma unroll
        for (int j = 0; j < 4; ++j) {
            const float4 v = *(const float4*)(V + f0 + 4 * j);
            sv += v.x + v.y + v.z + v.w;
            mv[j].x = -2.f * v.x; mv[j].y = -2.f * v.y;
            mv[j].z = -2.f * v.z; mv[j].w = -2.f * v.w;
            u0[j] = *(const float4*)(uh0 + f0 + 4 * j);
            u1[j] = *(const float4*)(uh1 + f0 + 4 * j);
        }
        const float* wsb = Ws + (b * TEn + wave * 64) * HEn;
        #pragma unroll 2
        for (int ci = 0; ci < 8; ++ci) {
            const float* wp = wsb + (ci * 8 + s_sub) * HEn + f0;
            float x0 = sv, x1 = sv;
            #pragma unroll
            for (int j = 0; j < 4; ++j) {
                const float4 w = ((const float4*)wp)[j];   // one load, two chains
                float r;
                r = __builtin_amdgcn_rcpf(__builtin_amdgcn_exp2f(w.x + u0[j].x) + 1.f);
                x0 = fmaf(mv[j].x, r, x0);
                r = __builtin_amdgcn_rcpf(__builtin_amdgcn_exp2f(w.x + u1[j].x) + 1.f);
                x1 = fmaf(mv[j].x, r, x1);
                r = __builtin_amdgcn_rcpf(__builtin_amdgcn_exp2f(w.y + u0[j].y) + 1.f);
                x0 = fmaf(mv[j].y, r, x0);
                r = __builtin_amdgcn_rcpf(__builtin_amdgcn_exp2f(w.y + u1[j].y) + 1.f);
                x1 = fmaf(mv[j].y, r, x1);
                r = __builtin_amdgcn_rcpf(__builtin_amdgcn_exp2f(w.z + u0[j].z) + 1.f);
                x0 = fmaf(mv[j].z, r, x0);
                r = __builtin_amdgcn_rcpf(__builtin_amdgcn_exp2f(w.z + u1[j].z) + 1.f);
                x1 = fmaf(mv[j].z, r, x1);
                r = __builtin_amdgcn_rcpf(__builtin_amdgcn_exp2f(w.w + u0[j].w) + 1.f);
                x0 = fmaf(mv[j].w, r, x0);
                r = __builtin_amdgcn_rcpf(__builtin_amdgcn_exp2f(w.w + u1[j].w) + 1.f);
                x1 = fmaf(mv[j].w, r, x1);
            }
            x0 += __shfl_xor(x0, 8, 64);
            x1 += __shfl_xor(x1, 8, 64);
            x0 += __shfl_xor(x0, 16, 64);
            x1 += __shfl_xor(x1, 16, 64);
            x0 += __shfl_xor(x0, 32, 64);
            x1 += __shfl_xor(x1, 32, 64);
            if (lane < 8) {
                sc0[wave * 64 + ci * 8 + lane] = x0;
                sc1[wave * 64 + ci * 8 + lane] = x1;
            }
        }
    }
    __syncthreads();

    // ---- softmax over both rows; thread tid owns s = tid
    {
        const float v0 = sc0[tid];
        const float v1 = sc1[tid];
        float m0 = v0, m1 = v1;
        #pragma unroll
        for (int off = 32; off; off >>= 1) {
            m0 = fmaxf(m0, __shfl_xor(m0, off, 64));
            m1 = fmaxf(m1, __shfl_xor(m1, off, 64));
        }
        if (lane == 0) { redm[0][wave] = m0; redm[1][wave] = m1; }
        __syncthreads();
        float bm0 = redm[0][0], bm1 = redm[1][0];
        #pragma unroll
        for (int w = 1; w < 8; ++w) {
            bm0 = fmaxf(bm0, redm[0][w]);
            bm1 = fmaxf(bm1, redm[1][w]);
        }
        const float ex0 = __builtin_amdgcn_exp2f((v0 - bm0) * LOG2E);
        const float ex1 = __builtin_amdgcn_exp2f((v1 - bm1) * LOG2E);
        float s0 = ex0, s1 = ex1;
        #pragma unroll
        for (int off = 32; off; off >>= 1) {
            s0 += __shfl_xor(s0, off, 64);
            s1 += __shfl_xor(s1, off, 64);
        }
        if (lane == 0) { reds[0][wave] = s0; reds[1][wave] = s1; }
        __syncthreads();
        float bs0 = reds[0][0], bs1 = reds[1][0];
        #pragma unroll
        for (int w = 1; w < 8; ++w) { bs0 += reds[0][w]; bs1 += reds[1][w]; }
        const float e0 = ex0 * __builtin_amdgcn_rcpf(bs0);
        const float e1 = ex1 * __builtin_amdgcn_rcpf(bs1);
        e_out[bt0 * TEn + tid]       = e0;
        e_out[(bt0 + 1) * TEn + tid] = e1;
        sc0[tid] = e0;               // same thread read this slot; no race
        sc1[tid] = e1;
    }
    __syncthreads();

    // ---- context: c[bt0+r, h] = sum_s e_r[s] * enc[b, s, h]
    // thread = (hl = tid&31 -> h = 4*hl..) x (sp = tid>>5, 32 s each)
    {
        const int hl = tid & 31;
        const int sp = tid >> 5;                      // 0..15
        const float* eb = enc + (b * TEn + sp * 32) * HEn + hl * 4;
        float4 a0 = {0,0,0,0}, a1 = {0,0,0,0};
        #pragma unroll 4
        for (int i = 0; i < 32; ++i) {
            const int s = sp * 32 + i;
            const float4 ev = *(const float4*)(eb + i * HEn);  // one load, 2 accs
            const float w0 = sc0[s], w1 = sc1[s];
            a0.x = fmaf(w0, ev.x, a0.x); a1.x = fmaf(w1, ev.x, a1.x);
            a0.y = fmaf(w0, ev.y, a0.y); a1.y = fmaf(w1, ev.y, a1.y);
            a0.z = fmaf(w0, ev.z, a0.z); a1.z = fmaf(w1, ev.z, a1.z);
            a0.w = fmaf(w0, ev.w, a0.w); a1.w = fmaf(w1, ev.w, a1.w);
        }
        *(float4*)&part[sp][hl * 4]       = a0;
        *(float4*)&part[sp][HEn + hl * 4] = a1;
    }
    __syncthreads();
    if (tid < 2 * HEn) {
        const int r = tid >> 7, h = tid & 127;
        float s = 0.f;
        #pragma unroll
        for (int p = 0; p < 16; ++p) s += part[p][r * HEn + h];
        c_out[(bt0 + r) * HEn + h] = s;
    }
}

extern "C" void kernel_launch(void* const* d_in, const int* in_sizes, int n_in,
                              void* d_out, int out_size, void* d_ws, size_t ws_size,
                              hipStream_t stream) {
    const float* enc = (const float*)d_in[0];   // [B,TE,HE]
    const float* dec = (const float*)d_in[1];   // [B,TD,HD]
    const float* W   = (const float*)d_in[2];   // [HE,HE]
    const float* U   = (const float*)d_in[3];   // [HD,HE]
    const float* V   = (const float*)d_in[4];   // [HE,1]
    float* out   = (float*)d_out;
    float* c_out = out;                         // [B,TD,HE]
    float* e_out = out + Bn * TDn * HEn;        // [B,TD,TE]
    float* Ws    = (float*)d_ws;                // [B,TE,HE] scratch, 1 MB (K2-scaled)

    ws_gemm_kernel<<<Bn * TEn / 8, 512, 0, stream>>>(enc, W, Ws);
    attn_kernel<<<Bn * TDn / 2, 512, 0, stream>>>(enc, dec, U, V, Ws, c_out, e_out);
}